// Round 3
// baseline (1258.393 us; speedup 1.0000x reference)
//
#include <hip/hip_runtime.h>

// ---------------- dtype probe: int64 vs int32 indices ----------------
// If an index tensor is int64 (nonneg, < 2^31), every odd int32 word is 0.
__global__ void k_detect(const int* __restrict__ ei, const int* __restrict__ tn,
                         int* __restrict__ flags) {
    if (threadIdx.x == 0 && blockIdx.x == 0) {
        int orv = 0;
        for (int i = 1; i < 64; i += 2) orv |= ei[i];
        flags[0] = (orv == 0) ? 1 : 0;
        int orv2 = 0;
        for (int i = 1; i < 64; i += 2) orv2 |= tn[i];
        flags[1] = (orv2 == 0) ? 1 : 0;
    }
}

// ---------------- graph build ----------------

__global__ void k_count(const int* __restrict__ ei, const int* __restrict__ flags,
                        int* __restrict__ cnt, int E) {
    int e = blockIdx.x * 256 + threadIdx.x;
    if (e < E) {
        int m = flags[0];
        int r = ei[(size_t)e << m];
        atomicAdd(&cnt[r], 1);
    }
}

__global__ void k_bsum(const int* __restrict__ cnt, int* __restrict__ bsums, int N) {
    __shared__ int s[256];
    int t = threadIdx.x;
    int i = blockIdx.x * 256 + t;
    int v = (i < N) ? cnt[i] : 0;
    s[t] = v; __syncthreads();
    for (int off = 128; off > 0; off >>= 1) {
        if (t < off) s[t] += s[t + off];
        __syncthreads();
    }
    if (t == 0) bsums[blockIdx.x] = s[0];
}

__global__ void k_btop(const int* __restrict__ bsums, int* __restrict__ btops, int NB) {
    __shared__ int s[256];
    int t = threadIdx.x;
    int v = (t < NB) ? bsums[t] : 0;
    s[t] = v; __syncthreads();
    for (int off = 1; off < 256; off <<= 1) {
        int x = (t >= off) ? s[t - off] : 0;
        __syncthreads();
        s[t] += x;
        __syncthreads();
    }
    btops[t] = s[t] - v;  // exclusive
}

__global__ void k_scan3(const int* __restrict__ cnt, const int* __restrict__ btops,
                        int* __restrict__ rowptr, int* __restrict__ cursor,
                        float* __restrict__ disq, int N, int E) {
    __shared__ int s[256];
    int t = threadIdx.x;
    int i = blockIdx.x * 256 + t;
    int v = (i < N) ? cnt[i] : 0;
    s[t] = v; __syncthreads();
    for (int off = 1; off < 256; off <<= 1) {
        int x = (t >= off) ? s[t - off] : 0;
        __syncthreads();
        s[t] += x;
        __syncthreads();
    }
    int excl = s[t] - v + btops[blockIdx.x];
    if (i < N) {
        rowptr[i] = excl;
        cursor[i] = excl;
        disq[i] = rsqrtf((float)(v + 1));  // +1 self loop
        if (i == N - 1) rowptr[N] = E;
    }
}

__global__ void k_fill(const int* __restrict__ ei, const int* __restrict__ flags,
                       int* __restrict__ cursor, int* __restrict__ ssrc, int E) {
    int e = blockIdx.x * 256 + threadIdx.x;
    if (e < E) {
        int m = flags[0];
        int r = ei[(size_t)e << m];
        int c = ei[(size_t)(E + e) << m];
        int p = atomicAdd(&cursor[r], 1);
        ssrc[p] = c;
    }
}

// ---------------- fp32 GEMM: C[M][256] = A[M][K] @ W[K][256] ----------------
// Block = 256 thr = 4 waves. Wave w handles 8 rows; lane = 4 cols.
// W rows streamed (L1/L2-resident, shared across waves); A reused 8x.

__global__ __launch_bounds__(256) void k_gemm(
        const float* __restrict__ A, const float* __restrict__ W, float* __restrict__ C,
        const int* __restrict__ idx, const int* __restrict__ flags,
        int M, int K, const float* __restrict__ bias, int relu) {
    int wave = threadIdx.x >> 6;
    int lane = threadIdx.x & 63;
    int n4 = lane * 4;
    int m0 = blockIdx.x * 32 + wave * 8;
    if (m0 >= M) return;
    int f = idx ? flags[1] : 0;

    const float* Ap[8];
#pragma unroll
    for (int r = 0; r < 8; r++) {
        int m = m0 + r; if (m >= M) m = M - 1;
        int arow = idx ? idx[(size_t)m << f] : m;
        Ap[r] = A + (size_t)arow * K;
    }

    float4 acc[8];
#pragma unroll
    for (int r = 0; r < 8; r++) acc[r] = make_float4(0.f, 0.f, 0.f, 0.f);

    for (int k0 = 0; k0 < K; k0 += 4) {
        float4 a[8];
#pragma unroll
        for (int r = 0; r < 8; r++) a[r] = *(const float4*)(Ap[r] + k0);
#pragma unroll
        for (int kk = 0; kk < 4; kk++) {
            float4 wv = *(const float4*)(W + (size_t)(k0 + kk) * 256 + n4);
#pragma unroll
            for (int r = 0; r < 8; r++) {
                float av = (kk == 0) ? a[r].x : (kk == 1) ? a[r].y : (kk == 2) ? a[r].z : a[r].w;
                acc[r].x += av * wv.x;
                acc[r].y += av * wv.y;
                acc[r].z += av * wv.z;
                acc[r].w += av * wv.w;
            }
        }
    }

    float4 bv = make_float4(0.f, 0.f, 0.f, 0.f);
    if (bias) bv = *(const float4*)(bias + n4);
#pragma unroll
    for (int r = 0; r < 8; r++) {
        int m = m0 + r;
        if (m >= M) break;
        float4 o = acc[r];
        o.x += bv.x; o.y += bv.y; o.z += bv.z; o.w += bv.w;
        if (relu) {
            o.x = fmaxf(o.x, 0.f); o.y = fmaxf(o.y, 0.f);
            o.z = fmaxf(o.z, 0.f); o.w = fmaxf(o.w, 0.f);
        }
        *(float4*)(C + (size_t)m * 256 + n4) = o;
    }
}

// ---------------- CSR gather-aggregate (one wave per destination) ----------------

__global__ void k_gather(const float* __restrict__ hW, const int* __restrict__ rowptr,
                         const int* __restrict__ ssrc, const float* __restrict__ disq,
                         float* __restrict__ agg, int N) {
    int wave = threadIdx.x >> 6;
    int lane = threadIdx.x & 63;
    int i = blockIdx.x * 4 + wave;
    if (i >= N) return;
    int f0 = lane * 4;
    float di = disq[i];
    float4 sv = *(const float4*)(hW + (size_t)i * 256 + f0);
    float self = di * di;
    float a0 = sv.x * self, a1 = sv.y * self, a2 = sv.z * self, a3 = sv.w * self;
    int s = rowptr[i], e = rowptr[i + 1];
    for (int p = s; p < e; p++) {
        int c = ssrc[p];
        float w = di * disq[c];
        float4 v = *(const float4*)(hW + (size_t)c * 256 + f0);
        a0 += w * v.x;
        a1 += w * v.y;
        a2 += w * v.z;
        a3 += w * v.w;
    }
    *(float4*)(agg + (size_t)i * 256 + f0) = make_float4(a0, a1, a2, a3);
}

// ---------------- BN stats + apply (in-place agg -> h) ----------------

__global__ void k_bnstat(const float* __restrict__ agg, float* __restrict__ stat, int N) {
    int f = threadIdx.x;
    int r0 = blockIdx.x * 256;
    int r1 = min(r0 + 256, N);
    float s = 0.f, s2 = 0.f;
    for (int r = r0; r < r1; r++) {
        float v = agg[(size_t)r * 256 + f];
        s += v; s2 += v * v;
    }
    atomicAdd(&stat[f], s);
    atomicAdd(&stat[256 + f], s2);
}

__global__ void k_bnapply(float* __restrict__ agg, const float* __restrict__ stat,
                          const float* __restrict__ gamma, const float* __restrict__ beta,
                          int N, float invN) {
    size_t t = (size_t)blockIdx.x * 256 + threadIdx.x;
    size_t base = t * 4;
    if (base >= (size_t)N * 256) return;
    int f0 = (int)(base & 255);
    float4 v = *(float4*)(agg + base);
    float r[4] = {v.x, v.y, v.z, v.w};
    float o[4];
#pragma unroll
    for (int j = 0; j < 4; j++) {
        int f = f0 + j;
        float mean = stat[f] * invN;
        float var = stat[256 + f] * invN - mean * mean;
        float rstd = rsqrtf(var + 1e-5f);
        float sc = rstd * gamma[f];
        float sh = beta[f] - mean * sc;
        o[j] = fmaxf(r[j] * sc + sh, 0.0f);
    }
    *(float4*)(agg + base) = make_float4(o[0], o[1], o[2], o[3]);
}

// ---------------- final dot: out[t] = z[t,:] . Wf + bf ----------------

__global__ void k_dot(const float* __restrict__ z, const float* __restrict__ Wf,
                      const float* __restrict__ bf, float* __restrict__ out, int M) {
    int wave = threadIdx.x >> 6;
    int lane = threadIdx.x & 63;
    int t = blockIdx.x * 4 + wave;
    if (t >= M) return;
    int f0 = lane * 4;
    float4 zv = *(const float4*)(z + (size_t)t * 256 + f0);
    float4 wv = *(const float4*)(Wf + f0);
    float acc = zv.x * wv.x + zv.y * wv.y + zv.z * wv.z + zv.w * wv.w;
    for (int off = 32; off > 0; off >>= 1) acc += __shfl_down(acc, off, 64);
    if (lane == 0) out[t] = acc + bf[0];
}

// ---------------- host ----------------

extern "C" void kernel_launch(void* const* d_in, const int* in_sizes, int n_in,
                              void* d_out, int out_size, void* d_ws, size_t ws_size,
                              hipStream_t stream) {
    const int D = 128, H = 256;
    const int N = in_sizes[0] / D;   // 50000
    const int E = in_sizes[1] / 2;   // 800000
    const int M = in_sizes[2];       // 10000

    const float* x = (const float*)d_in[0];
    const int* ei = (const int*)d_in[1];        // edge_index (int32 or int64 low-words)
    const int* tnid = (const int*)d_in[2];
    const float* W1 = (const float*)d_in[3];
    const float* W2 = (const float*)d_in[5];
    const float* W3 = (const float*)d_in[7];
    const float* g1 = (const float*)d_in[9];
    const float* be1 = (const float*)d_in[10];
    const float* g2 = (const float*)d_in[11];
    const float* be2 = (const float*)d_in[12];
    const float* g3 = (const float*)d_in[13];
    const float* be3 = (const float*)d_in[14];
    const float* Wl = (const float*)d_in[15];
    const float* bl = (const float*)d_in[16];
    const float* Wf = (const float*)d_in[17];
    const float* bfp = (const float*)d_in[18];
    float* out = (float*)d_out;

    char* w = (char*)d_ws;
    size_t off = 0;
    auto carve = [&](size_t bytes) -> void* {
        void* p = w + off;
        off = (off + bytes + 255) & ~(size_t)255;
        return p;
    };

    int* deg = (int*)carve((size_t)N * 4);
    float* stat = (float*)carve(3 * 512 * 4);
    size_t zero_span = off;                     // deg + stats zeroed in one memset
    int* flags = (int*)carve(256);
    int* rowptr = (int*)carve((size_t)(N + 1) * 4);
    int* cursor = (int*)carve((size_t)N * 4);
    int* bsums = (int*)carve(256 * 4);
    int* btops = (int*)carve(256 * 4);
    float* disq = (float*)carve((size_t)N * 4);
    int* ssrc = (int*)carve((size_t)E * 4);
    float* hW = (float*)carve((size_t)N * H * 4);
    float* agg = (float*)carve((size_t)N * H * 4);   // doubles as h (BN applied in place)
    float* z = (float*)carve((size_t)M * H * 4);

    const int NB = (N + 255) / 256;             // 196
    const int EB = (E + 255) / 256;
    const float invN = 1.0f / (float)N;

    hipMemsetAsync(d_ws, 0, zero_span, stream);

    k_detect<<<1, 64, 0, stream>>>(ei, tnid, flags);
    k_count<<<EB, 256, 0, stream>>>(ei, flags, deg, E);
    k_bsum<<<NB, 256, 0, stream>>>(deg, bsums, N);
    k_btop<<<1, 256, 0, stream>>>(bsums, btops, NB);
    k_scan3<<<NB, 256, 0, stream>>>(deg, btops, rowptr, cursor, disq, N, E);
    k_fill<<<EB, 256, 0, stream>>>(ei, flags, cursor, ssrc, E);

    const int GB = (N + 31) / 32;               // 1563
    const int AB = (N + 3) / 4;                 // 12500
    const int PB = (int)(((size_t)N * H / 4 + 255) / 256);  // 12500

    // layer 1 (GCN bias cancels inside BatchNorm)
    k_gemm<<<GB, 256, 0, stream>>>(x, W1, hW, nullptr, flags, N, 128, nullptr, 0);
    k_gather<<<AB, 256, 0, stream>>>(hW, rowptr, ssrc, disq, agg, N);
    k_bnstat<<<NB, 256, 0, stream>>>(agg, stat, N);
    k_bnapply<<<PB, 256, 0, stream>>>(agg, stat, g1, be1, N, invN);
    // layer 2
    k_gemm<<<GB, 256, 0, stream>>>(agg, W2, hW, nullptr, flags, N, 256, nullptr, 0);
    k_gather<<<AB, 256, 0, stream>>>(hW, rowptr, ssrc, disq, agg, N);
    k_bnstat<<<NB, 256, 0, stream>>>(agg, stat + 512, N);
    k_bnapply<<<PB, 256, 0, stream>>>(agg, stat + 512, g2, be2, N, invN);
    // layer 3
    k_gemm<<<GB, 256, 0, stream>>>(agg, W3, hW, nullptr, flags, N, 256, nullptr, 0);
    k_gather<<<AB, 256, 0, stream>>>(hW, rowptr, ssrc, disq, agg, N);
    k_bnstat<<<NB, 256, 0, stream>>>(agg, stat + 1024, N);
    k_bnapply<<<PB, 256, 0, stream>>>(agg, stat + 1024, g3, be3, N, invN);

    // final: z = relu(agg[tnid] @ Wl + bl) ; out = z @ Wf + bf
    k_gemm<<<(M + 31) / 32, 256, 0, stream>>>(agg, Wl, z, tnid, flags, M, 256, bl, 1);
    k_dot<<<(M + 3) / 4, 256, 0, stream>>>(z, Wf, bfp, out, M);
}

// Round 4
// 862.366 us; speedup vs baseline: 1.4592x; 1.4592x over previous
//
#include <hip/hip_runtime.h>

typedef unsigned short u16;
typedef __attribute__((ext_vector_type(8))) short short8;
typedef __attribute__((ext_vector_type(4))) float f32x4;

#define DEVFN static __device__ __forceinline__

DEVFN float b2f(u16 u) {
    union { float f; unsigned v; } x; x.v = ((unsigned)u) << 16; return x.f;
}
DEVFN u16 f2b(float f) {
    union { float f; unsigned v; } x; x.f = f;
    unsigned r = x.v + 0x7fffu + ((x.v >> 16) & 1u);
    return (u16)(r >> 16);
}

// ---------------- dtype probe: int64 vs int32 indices ----------------
__global__ void k_detect(const int* __restrict__ ei, const int* __restrict__ tn,
                         int* __restrict__ flags) {
    if (threadIdx.x == 0 && blockIdx.x == 0) {
        int orv = 0;
        for (int i = 1; i < 64; i += 2) orv |= ei[i];
        flags[0] = (orv == 0) ? 1 : 0;
        int orv2 = 0;
        for (int i = 1; i < 64; i += 2) orv2 |= tn[i];
        flags[1] = (orv2 == 0) ? 1 : 0;
    }
}

// ---------------- graph build ----------------

__global__ void k_count(const int* __restrict__ ei, const int* __restrict__ flags,
                        int* __restrict__ cnt, int E) {
    int e = blockIdx.x * 256 + threadIdx.x;
    if (e < E) {
        int m = flags[0];
        atomicAdd(&cnt[ei[(size_t)e << m]], 1);
    }
}

__global__ void k_bsum(const int* __restrict__ cnt, int* __restrict__ bsums, int N) {
    __shared__ int s[256];
    int t = threadIdx.x;
    int i = blockIdx.x * 256 + t;
    int v = (i < N) ? cnt[i] : 0;
    s[t] = v; __syncthreads();
    for (int off = 128; off > 0; off >>= 1) {
        if (t < off) s[t] += s[t + off];
        __syncthreads();
    }
    if (t == 0) bsums[blockIdx.x] = s[0];
}

__global__ void k_btop(const int* __restrict__ bsums, int* __restrict__ btops, int NB) {
    __shared__ int s[256];
    int t = threadIdx.x;
    int v = (t < NB) ? bsums[t] : 0;
    s[t] = v; __syncthreads();
    for (int off = 1; off < 256; off <<= 1) {
        int x = (t >= off) ? s[t - off] : 0;
        __syncthreads();
        s[t] += x;
        __syncthreads();
    }
    btops[t] = s[t] - v;  // exclusive
}

__global__ void k_scan3(const int* __restrict__ cnt, const int* __restrict__ btops,
                        int* __restrict__ rowptr, int* __restrict__ cursor,
                        float* __restrict__ disq, int N, int E) {
    __shared__ int s[256];
    int t = threadIdx.x;
    int i = blockIdx.x * 256 + t;
    int v = (i < N) ? cnt[i] : 0;
    s[t] = v; __syncthreads();
    for (int off = 1; off < 256; off <<= 1) {
        int x = (t >= off) ? s[t - off] : 0;
        __syncthreads();
        s[t] += x;
        __syncthreads();
    }
    int excl = s[t] - v + btops[blockIdx.x];
    if (i < N) {
        rowptr[i] = excl;
        cursor[i] = excl;
        disq[i] = rsqrtf((float)(v + 1));  // +1 self loop
        if (i == N - 1) rowptr[N] = E;
    }
}

__global__ void k_fill(const int* __restrict__ ei, const int* __restrict__ flags,
                       int* __restrict__ cursor, int* __restrict__ ssrc, int E) {
    int e = blockIdx.x * 256 + threadIdx.x;
    if (e < E) {
        int m = flags[0];
        int r = ei[(size_t)e << m];
        int c = ei[(size_t)(E + e) << m];
        int p = atomicAdd(&cursor[r], 1);
        ssrc[p] = c;
    }
}

// ---------------- fp32 -> bf16 convert (x) ----------------
__global__ void k_cvtx(const float* __restrict__ x, u16* __restrict__ xb, int n) {
    int i = (blockIdx.x * 256 + threadIdx.x) * 4;
    if (i >= n) return;
    float4 v = *(const float4*)(x + i);
    ushort4 o;
    o.x = f2b(v.x); o.y = f2b(v.y); o.z = f2b(v.z); o.w = f2b(v.w);
    *(ushort4*)(xb + i) = o;
}

// ---------------- weight convert+transpose: T[n*K+k] = bf16(W[k*256+n]) ----------------
__global__ void k_wt(const float* __restrict__ W1, const float* __restrict__ W2,
                     const float* __restrict__ W3, const float* __restrict__ Wl,
                     u16* __restrict__ T1, u16* __restrict__ T2,
                     u16* __restrict__ T3, u16* __restrict__ Tl) {
    int t = blockIdx.x * 256 + threadIdx.x;  // 0 .. 229375
    const float* W; u16* T; int K; int idx;
    if (t < 32768)        { W = W1; T = T1; K = 128; idx = t; }
    else if (t < 98304)   { W = W2; T = T2; K = 256; idx = t - 32768; }
    else if (t < 163840)  { W = W3; T = T3; K = 256; idx = t - 98304; }
    else                  { W = Wl; T = Tl; K = 256; idx = t - 163840; }
    int k = idx >> 8, n = idx & 255;
    T[(size_t)n * K + k] = f2b(W[(size_t)k * 256 + n]);
}

// ---------------- MFMA GEMM: C[M][256] = A[M][K] @ W[K][256], bf16 in/out ----------------
// Wt[n][k] transposed weights (bf16, L2-resident). Block = 4 waves;
// each wave: 16 rows x 256 cols = 16 accum frags of 16x16x32 MFMA.

__global__ __launch_bounds__(256) void k_gemm(const u16* __restrict__ A,
                                              const u16* __restrict__ Wt,
                                              u16* __restrict__ C,
                                              const int* __restrict__ idx,
                                              const int* __restrict__ flags,
                                              int M, int K,
                                              const float* __restrict__ bias,
                                              int relu) {
    int wave = threadIdx.x >> 6;
    int lane = threadIdx.x & 63;
    int quad = lane >> 4;
    int mr = lane & 15;
    int m0 = blockIdx.x * 64 + wave * 16;
    if (m0 >= M) return;  // M is a multiple of 16, no partial wave-tiles

    int arow = m0 + mr;
    if (idx) arow = idx[(size_t)arow << flags[1]];
    const u16* Ap = A + (size_t)arow * K + quad * 8;
    const u16* Wp = Wt + (size_t)mr * K + quad * 8;

    f32x4 acc[16];
#pragma unroll
    for (int nt = 0; nt < 16; nt++) acc[nt] = (f32x4){0.f, 0.f, 0.f, 0.f};

    for (int k0 = 0; k0 < K; k0 += 32) {
        short8 a = *(const short8*)(Ap + k0);
#pragma unroll
        for (int nt = 0; nt < 16; nt++) {
            short8 b = *(const short8*)(Wp + (size_t)nt * 16 * K + k0);
            acc[nt] = __builtin_amdgcn_mfma_f32_16x16x32_bf16(a, b, acc[nt], 0, 0, 0);
        }
    }

    // C/D layout: col = lane&15 (within 16-tile), row = quad*4 + r  [verified mapping]
    size_t cbase = (size_t)(m0 + quad * 4) * 256 + mr;
#pragma unroll
    for (int nt = 0; nt < 16; nt++) {
        float bb = bias ? bias[nt * 16 + mr] : 0.0f;
#pragma unroll
        for (int r = 0; r < 4; r++) {
            float v = acc[nt][r] + bb;
            if (relu) v = fmaxf(v, 0.0f);
            C[cbase + (size_t)r * 256 + nt * 16] = f2b(v);
        }
    }
}

// ---------------- CSR gather-aggregate (one wave per destination, bf16 src) ----------------

__global__ void k_gather(const u16* __restrict__ hW, const int* __restrict__ rowptr,
                         const int* __restrict__ ssrc, const float* __restrict__ disq,
                         float* __restrict__ agg, int N) {
    int wave = threadIdx.x >> 6;
    int lane = threadIdx.x & 63;
    int i = blockIdx.x * 4 + wave;
    if (i >= N) return;
    int f0 = lane * 4;
    const u16* base = hW + f0;
    float di = disq[i];
    ushort4 sv = *(const ushort4*)(base + (size_t)i * 256);
    float self = di * di;
    float a0 = b2f(sv.x) * self, a1 = b2f(sv.y) * self;
    float a2 = b2f(sv.z) * self, a3 = b2f(sv.w) * self;
    int s = rowptr[i], e = rowptr[i + 1];
    if (s < e) {
        int c = ssrc[s];
        for (int p = s; p < e; p++) {
            int cn = (p + 1 < e) ? ssrc[p + 1] : 0;   // prefetch next index
            float w = di * disq[c];
            ushort4 v = *(const ushort4*)(base + (size_t)c * 256);
            a0 += w * b2f(v.x);
            a1 += w * b2f(v.y);
            a2 += w * b2f(v.z);
            a3 += w * b2f(v.w);
            c = cn;
        }
    }
    *(float4*)(agg + (size_t)i * 256 + f0) = make_float4(a0, a1, a2, a3);
}

// ---------------- BN stats (fp32) + apply -> bf16 h ----------------

__global__ void k_bnstat(const float* __restrict__ agg, float* __restrict__ stat, int N) {
    int f = threadIdx.x;
    int r0 = blockIdx.x * 64;
    int r1 = min(r0 + 64, N);
    float s = 0.f, s2 = 0.f;
    for (int r = r0; r < r1; r++) {
        float v = agg[(size_t)r * 256 + f];
        s += v; s2 += v * v;
    }
    atomicAdd(&stat[f], s);
    atomicAdd(&stat[256 + f], s2);
}

__global__ void k_bnapply(const float* __restrict__ agg, const float* __restrict__ stat,
                          const float* __restrict__ gamma, const float* __restrict__ beta,
                          u16* __restrict__ h, int N, float invN) {
    size_t t = (size_t)blockIdx.x * 256 + threadIdx.x;
    size_t base = t * 4;
    if (base >= (size_t)N * 256) return;
    int f0 = (int)(base & 255);
    float4 v = *(const float4*)(agg + base);
    float r[4] = {v.x, v.y, v.z, v.w};
    ushort4 o;
    u16* op = (u16*)&o;
#pragma unroll
    for (int j = 0; j < 4; j++) {
        int f = f0 + j;
        float mean = stat[f] * invN;
        float var = stat[256 + f] * invN - mean * mean;
        float rstd = rsqrtf(var + 1e-5f);
        float sc = rstd * gamma[f];
        float sh = beta[f] - mean * sc;
        op[j] = f2b(fmaxf(r[j] * sc + sh, 0.0f));
    }
    *(ushort4*)(h + base) = o;
}

// ---------------- final dot: out[t] = z[t,:] . Wf + bf ----------------

__global__ void k_dot(const u16* __restrict__ z, const float* __restrict__ Wf,
                      const float* __restrict__ bf, float* __restrict__ out, int M) {
    int wave = threadIdx.x >> 6;
    int lane = threadIdx.x & 63;
    int t = blockIdx.x * 4 + wave;
    if (t >= M) return;
    int f0 = lane * 4;
    ushort4 zv = *(const ushort4*)(z + (size_t)t * 256 + f0);
    float4 wv = *(const float4*)(Wf + f0);
    float acc = b2f(zv.x) * wv.x + b2f(zv.y) * wv.y +
                b2f(zv.z) * wv.z + b2f(zv.w) * wv.w;
    for (int off = 32; off > 0; off >>= 1) acc += __shfl_down(acc, off, 64);
    if (lane == 0) out[t] = acc + bf[0];
}

// ---------------- host ----------------

extern "C" void kernel_launch(void* const* d_in, const int* in_sizes, int n_in,
                              void* d_out, int out_size, void* d_ws, size_t ws_size,
                              hipStream_t stream) {
    const int D = 128, H = 256;
    const int N = in_sizes[0] / D;   // 50000
    const int E = in_sizes[1] / 2;   // 800000
    const int M = in_sizes[2];       // 10000

    const float* x = (const float*)d_in[0];
    const int* ei = (const int*)d_in[1];
    const int* tnid = (const int*)d_in[2];
    const float* W1 = (const float*)d_in[3];
    const float* W2 = (const float*)d_in[5];
    const float* W3 = (const float*)d_in[7];
    const float* g1 = (const float*)d_in[9];
    const float* be1 = (const float*)d_in[10];
    const float* g2 = (const float*)d_in[11];
    const float* be2 = (const float*)d_in[12];
    const float* g3 = (const float*)d_in[13];
    const float* be3 = (const float*)d_in[14];
    const float* Wl = (const float*)d_in[15];
    const float* bl = (const float*)d_in[16];
    const float* Wf = (const float*)d_in[17];
    const float* bfp = (const float*)d_in[18];
    float* out = (float*)d_out;

    char* w = (char*)d_ws;
    size_t off = 0;
    auto carve = [&](size_t bytes) -> void* {
        void* p = w + off;
        off = (off + bytes + 255) & ~(size_t)255;
        return p;
    };

    int* deg = (int*)carve((size_t)N * 4);
    float* stat = (float*)carve(3 * 512 * 4);
    size_t zero_span = off;                     // deg + stats zeroed in one memset
    int* flags = (int*)carve(256);
    int* rowptr = (int*)carve((size_t)(N + 1) * 4);
    int* cursor = (int*)carve((size_t)N * 4);
    int* bsums = (int*)carve(256 * 4);
    int* btops = (int*)carve(256 * 4);
    float* disq = (float*)carve((size_t)N * 4);
    int* ssrc = (int*)carve((size_t)E * 4);
    u16* Wt1 = (u16*)carve((size_t)H * D * 2);
    u16* Wt2 = (u16*)carve((size_t)H * H * 2);
    u16* Wt3 = (u16*)carve((size_t)H * H * 2);
    u16* Wtl = (u16*)carve((size_t)H * H * 2);
    u16* xb = (u16*)carve((size_t)N * D * 2);   // also reused as z (final, M*H*2 <= N*D*2)
    u16* hW = (u16*)carve((size_t)N * H * 2);   // GEMM output (pre-aggregation), bf16
    float* agg = (float*)carve((size_t)N * H * 4);
    u16* hb = (u16*)carve((size_t)N * H * 2);   // post-BN h, bf16
    u16* z = xb;

    const int NB = (N + 255) / 256;
    const int EB = (E + 255) / 256;
    const float invN = 1.0f / (float)N;

    hipMemsetAsync(d_ws, 0, zero_span, stream);

    k_detect<<<1, 64, 0, stream>>>(ei, tnid, flags);
    k_count<<<EB, 256, 0, stream>>>(ei, flags, deg, E);
    k_bsum<<<NB, 256, 0, stream>>>(deg, bsums, N);
    k_btop<<<1, 256, 0, stream>>>(bsums, btops, NB);
    k_scan3<<<NB, 256, 0, stream>>>(deg, btops, rowptr, cursor, disq, N, E);
    k_fill<<<EB, 256, 0, stream>>>(ei, flags, cursor, ssrc, E);
    k_cvtx<<<(N * D / 4 + 255) / 256, 256, 0, stream>>>(x, xb, N * D);
    k_wt<<<896, 256, 0, stream>>>(W1, W2, W3, Wl, Wt1, Wt2, Wt3, Wtl);

    const int GB = (N + 63) / 64;               // 782 (16-row wave tiles, 4 waves/block)
    const int AB = (N + 3) / 4;                 // 12500
    const int SB = (N + 63) / 64;               // 782 bnstat blocks
    const int PB = (int)(((size_t)N * H / 4 + 255) / 256);  // 12500

    // layer 1 (GCN bias cancels inside BatchNorm)
    k_gemm<<<GB, 256, 0, stream>>>(xb, Wt1, hW, nullptr, flags, N, 128, nullptr, 0);
    k_gather<<<AB, 256, 0, stream>>>(hW, rowptr, ssrc, disq, agg, N);
    k_bnstat<<<SB, 256, 0, stream>>>(agg, stat, N);
    k_bnapply<<<PB, 256, 0, stream>>>(agg, stat, g1, be1, hb, N, invN);
    // layer 2
    k_gemm<<<GB, 256, 0, stream>>>(hb, Wt2, hW, nullptr, flags, N, 256, nullptr, 0);
    k_gather<<<AB, 256, 0, stream>>>(hW, rowptr, ssrc, disq, agg, N);
    k_bnstat<<<SB, 256, 0, stream>>>(agg, stat + 512, N);
    k_bnapply<<<PB, 256, 0, stream>>>(agg, stat + 512, g2, be2, hb, N, invN);
    // layer 3
    k_gemm<<<GB, 256, 0, stream>>>(hb, Wt3, hW, nullptr, flags, N, 256, nullptr, 0);
    k_gather<<<AB, 256, 0, stream>>>(hW, rowptr, ssrc, disq, agg, N);
    k_bnstat<<<SB, 256, 0, stream>>>(agg, stat + 1024, N);
    k_bnapply<<<PB, 256, 0, stream>>>(agg, stat + 1024, g3, be3, hb, N, invN);

    // final: z = relu(hb[tnid] @ Wl + bl) ; out = z @ Wf + bf
    k_gemm<<<(M + 63) / 64, 256, 0, stream>>>(hb, Wtl, z, tnid, flags, M, 256, bl, 1);
    k_dot<<<(M + 3) / 4, 256, 0, stream>>>(z, Wf, bfp, out, M);
}

// Round 5
// 749.396 us; speedup vs baseline: 1.6792x; 1.1507x over previous
//
#include <hip/hip_runtime.h>

typedef unsigned short u16;
typedef __attribute__((ext_vector_type(8))) short short8;
typedef __attribute__((ext_vector_type(4))) float f32x4;

#define DEVFN static __device__ __forceinline__

DEVFN float b2f(u16 u) {
    union { float f; unsigned v; } x; x.v = ((unsigned)u) << 16; return x.f;
}
DEVFN u16 f2b(float f) {
    union { float f; unsigned v; } x; x.f = f;
    unsigned r = x.v + 0x7fffu + ((x.v >> 16) & 1u);
    return (u16)(r >> 16);
}

// ---------------- dtype probe: int64 vs int32 indices ----------------
__global__ void k_detect(const int* __restrict__ ei, const int* __restrict__ tn,
                         int* __restrict__ flags) {
    if (threadIdx.x == 0 && blockIdx.x == 0) {
        int orv = 0;
        for (int i = 1; i < 64; i += 2) orv |= ei[i];
        flags[0] = (orv == 0) ? 1 : 0;
        int orv2 = 0;
        for (int i = 1; i < 64; i += 2) orv2 |= tn[i];
        flags[1] = (orv2 == 0) ? 1 : 0;
    }
}

// ---------------- graph build ----------------

__global__ void k_count(const int* __restrict__ ei, const int* __restrict__ flags,
                        int* __restrict__ cnt, int E) {
    int e = blockIdx.x * 256 + threadIdx.x;
    if (e < E) {
        int m = flags[0];
        atomicAdd(&cnt[ei[(size_t)e << m]], 1);
    }
}

__global__ void k_bsum(const int* __restrict__ cnt, int* __restrict__ bsums, int N) {
    __shared__ int s[256];
    int t = threadIdx.x;
    int i = blockIdx.x * 256 + t;
    int v = (i < N) ? cnt[i] : 0;
    s[t] = v; __syncthreads();
    for (int off = 128; off > 0; off >>= 1) {
        if (t < off) s[t] += s[t + off];
        __syncthreads();
    }
    if (t == 0) bsums[blockIdx.x] = s[0];
}

__global__ void k_btop(const int* __restrict__ bsums, int* __restrict__ btops, int NB) {
    __shared__ int s[256];
    int t = threadIdx.x;
    int v = (t < NB) ? bsums[t] : 0;
    s[t] = v; __syncthreads();
    for (int off = 1; off < 256; off <<= 1) {
        int x = (t >= off) ? s[t - off] : 0;
        __syncthreads();
        s[t] += x;
        __syncthreads();
    }
    btops[t] = s[t] - v;  // exclusive
}

__global__ void k_scan3(const int* __restrict__ cnt, const int* __restrict__ btops,
                        int* __restrict__ rowptr, int* __restrict__ cursor,
                        float* __restrict__ disq, int N, int E) {
    __shared__ int s[256];
    int t = threadIdx.x;
    int i = blockIdx.x * 256 + t;
    int v = (i < N) ? cnt[i] : 0;
    s[t] = v; __syncthreads();
    for (int off = 1; off < 256; off <<= 1) {
        int x = (t >= off) ? s[t - off] : 0;
        __syncthreads();
        s[t] += x;
        __syncthreads();
    }
    int excl = s[t] - v + btops[blockIdx.x];
    if (i < N) {
        rowptr[i] = excl;
        cursor[i] = excl;
        disq[i] = rsqrtf((float)(v + 1));  // +1 self loop
        if (i == N - 1) rowptr[N] = E;
    }
}

__global__ void k_fill(const int* __restrict__ ei, const int* __restrict__ flags,
                       int* __restrict__ cursor, int* __restrict__ ssrc, int E) {
    int e = blockIdx.x * 256 + threadIdx.x;
    if (e < E) {
        int m = flags[0];
        int r = ei[(size_t)e << m];
        int c = ei[(size_t)(E + e) << m];
        int p = atomicAdd(&cursor[r], 1);
        ssrc[p] = c;
    }
}

// ---------------- fp32 -> bf16 convert + pre-scale by disq[row] (x, 128 feat) ----------------
__global__ void k_cvtx(const float* __restrict__ x, const float* __restrict__ disq,
                       u16* __restrict__ xb, int n) {
    int i = (blockIdx.x * 256 + threadIdx.x) * 4;
    if (i >= n) return;
    float d = disq[i >> 7];
    float4 v = *(const float4*)(x + i);
    ushort4 o;
    o.x = f2b(v.x * d); o.y = f2b(v.y * d); o.z = f2b(v.z * d); o.w = f2b(v.w * d);
    *(ushort4*)(xb + i) = o;
}

// ---------------- weight convert+transpose: T[n*K+k] = bf16(W[k*256+n]) ----------------
__global__ void k_wt(const float* __restrict__ W1, const float* __restrict__ W2,
                     const float* __restrict__ W3, const float* __restrict__ Wl,
                     u16* __restrict__ T1, u16* __restrict__ T2,
                     u16* __restrict__ T3, u16* __restrict__ Tl) {
    int t = blockIdx.x * 256 + threadIdx.x;  // 0 .. 229375
    const float* W; u16* T; int K; int idx;
    if (t < 32768)        { W = W1; T = T1; K = 128; idx = t; }
    else if (t < 98304)   { W = W2; T = T2; K = 256; idx = t - 32768; }
    else if (t < 163840)  { W = W3; T = T3; K = 256; idx = t - 98304; }
    else                  { W = Wl; T = Tl; K = 256; idx = t - 163840; }
    int k = idx >> 8, n = idx & 255;
    T[(size_t)n * K + k] = f2b(W[(size_t)k * 256 + n]);
}

// ---------------- MFMA GEMM: C[M][256] = A[M][K] @ W[K][256], bf16 in/out ----------------

__global__ __launch_bounds__(256) void k_gemm(const u16* __restrict__ A,
                                              const u16* __restrict__ Wt,
                                              u16* __restrict__ C,
                                              const int* __restrict__ idx,
                                              const int* __restrict__ flags,
                                              int M, int K,
                                              const float* __restrict__ bias,
                                              int relu) {
    int wave = threadIdx.x >> 6;
    int lane = threadIdx.x & 63;
    int quad = lane >> 4;
    int mr = lane & 15;
    int m0 = blockIdx.x * 64 + wave * 16;
    if (m0 >= M) return;

    int arow = m0 + mr;
    if (idx) arow = idx[(size_t)arow << flags[1]];
    const u16* Ap = A + (size_t)arow * K + quad * 8;
    const u16* Wp = Wt + (size_t)mr * K + quad * 8;

    f32x4 acc[16];
#pragma unroll
    for (int nt = 0; nt < 16; nt++) acc[nt] = (f32x4){0.f, 0.f, 0.f, 0.f};

    for (int k0 = 0; k0 < K; k0 += 32) {
        short8 a = *(const short8*)(Ap + k0);
#pragma unroll
        for (int nt = 0; nt < 16; nt++) {
            short8 b = *(const short8*)(Wp + (size_t)nt * 16 * K + k0);
            acc[nt] = __builtin_amdgcn_mfma_f32_16x16x32_bf16(a, b, acc[nt], 0, 0, 0);
        }
    }

    // C/D layout: col = lane&15 (within 16-tile), row = quad*4 + r
    size_t cbase = (size_t)(m0 + quad * 4) * 256 + mr;
#pragma unroll
    for (int nt = 0; nt < 16; nt++) {
        float bb = bias ? bias[nt * 16 + mr] : 0.0f;
#pragma unroll
        for (int r = 0; r < 4; r++) {
            float v = acc[nt][r] + bb;
            if (relu) v = fmaxf(v, 0.0f);
            C[cbase + (size_t)r * 256 + nt * 16] = f2b(v);
        }
    }
}

// ---------------- CSR gather: dst[i] = disq[i] * (src[i] + sum_c src[c]) ----------------
// src rows pre-scaled by disq. 256-feature variant: 1 wave/row, 4 feats/lane,
// neighbor loop unrolled x4 for MLP.

__global__ __launch_bounds__(256) void k_gather256(
        const u16* __restrict__ src, const int* __restrict__ rowptr,
        const int* __restrict__ ssrc, const float* __restrict__ disq,
        u16* __restrict__ dst, int N) {
    int wave = threadIdx.x >> 6;
    int lane = threadIdx.x & 63;
    int i = blockIdx.x * 4 + wave;
    if (i >= N) return;
    int f0 = lane * 4;
    const u16* base = src + f0;
    ushort4 sv = *(const ushort4*)(base + (size_t)i * 256);
    float a0 = b2f(sv.x), a1 = b2f(sv.y), a2 = b2f(sv.z), a3 = b2f(sv.w);
    int s = rowptr[i], e = rowptr[i + 1];
    int p = s;
    for (; p + 4 <= e; p += 4) {
        int c0 = ssrc[p], c1 = ssrc[p + 1], c2 = ssrc[p + 2], c3 = ssrc[p + 3];
        ushort4 v0 = *(const ushort4*)(base + (size_t)c0 * 256);
        ushort4 v1 = *(const ushort4*)(base + (size_t)c1 * 256);
        ushort4 v2 = *(const ushort4*)(base + (size_t)c2 * 256);
        ushort4 v3 = *(const ushort4*)(base + (size_t)c3 * 256);
        a0 += (b2f(v0.x) + b2f(v1.x)) + (b2f(v2.x) + b2f(v3.x));
        a1 += (b2f(v0.y) + b2f(v1.y)) + (b2f(v2.y) + b2f(v3.y));
        a2 += (b2f(v0.z) + b2f(v1.z)) + (b2f(v2.z) + b2f(v3.z));
        a3 += (b2f(v0.w) + b2f(v1.w)) + (b2f(v2.w) + b2f(v3.w));
    }
    for (; p < e; p++) {
        int c = ssrc[p];
        ushort4 v = *(const ushort4*)(base + (size_t)c * 256);
        a0 += b2f(v.x); a1 += b2f(v.y); a2 += b2f(v.z); a3 += b2f(v.w);
    }
    float di = disq[i];
    ushort4 o;
    o.x = f2b(a0 * di); o.y = f2b(a1 * di); o.z = f2b(a2 * di); o.w = f2b(a3 * di);
    *(ushort4*)(dst + (size_t)i * 256 + f0) = o;
}

// 128-feature variant (layer-1 input x'): 2 feats/lane.
__global__ __launch_bounds__(256) void k_gather128(
        const u16* __restrict__ src, const int* __restrict__ rowptr,
        const int* __restrict__ ssrc, const float* __restrict__ disq,
        u16* __restrict__ dst, int N) {
    int wave = threadIdx.x >> 6;
    int lane = threadIdx.x & 63;
    int i = blockIdx.x * 4 + wave;
    if (i >= N) return;
    int f0 = lane * 2;
    const u16* base = src + f0;
    ushort2 sv = *(const ushort2*)(base + (size_t)i * 128);
    float a0 = b2f(sv.x), a1 = b2f(sv.y);
    int s = rowptr[i], e = rowptr[i + 1];
    int p = s;
    for (; p + 4 <= e; p += 4) {
        int c0 = ssrc[p], c1 = ssrc[p + 1], c2 = ssrc[p + 2], c3 = ssrc[p + 3];
        ushort2 v0 = *(const ushort2*)(base + (size_t)c0 * 128);
        ushort2 v1 = *(const ushort2*)(base + (size_t)c1 * 128);
        ushort2 v2 = *(const ushort2*)(base + (size_t)c2 * 128);
        ushort2 v3 = *(const ushort2*)(base + (size_t)c3 * 128);
        a0 += (b2f(v0.x) + b2f(v1.x)) + (b2f(v2.x) + b2f(v3.x));
        a1 += (b2f(v0.y) + b2f(v1.y)) + (b2f(v2.y) + b2f(v3.y));
    }
    for (; p < e; p++) {
        int c = ssrc[p];
        ushort2 v = *(const ushort2*)(base + (size_t)c * 128);
        a0 += b2f(v.x); a1 += b2f(v.y);
    }
    float di = disq[i];
    ushort2 o;
    o.x = f2b(a0 * di); o.y = f2b(a1 * di);
    *(ushort2*)(dst + (size_t)i * 128 + f0) = o;
}

// ---------------- BN stats (fp32 accum over bf16 t) ----------------

__global__ void k_bnstat(const u16* __restrict__ t, float* __restrict__ stat, int N) {
    int f = threadIdx.x;
    int r0 = blockIdx.x * 64;
    int r1 = min(r0 + 64, N);
    float s = 0.f, s2 = 0.f;
    for (int r = r0; r < r1; r++) {
        float v = b2f(t[(size_t)r * 256 + f]);
        s += v; s2 += v * v;
    }
    atomicAdd(&stat[f], s);
    atomicAdd(&stat[256 + f], s2);
}

// ---------------- BN apply + relu (+ optional disq pre-scale) -> bf16 h ----------------

__global__ void k_bnapply(const u16* __restrict__ t, const float* __restrict__ stat,
                          const float* __restrict__ gamma, const float* __restrict__ beta,
                          u16* __restrict__ h, int N, float invN,
                          const float* __restrict__ scale) {
    size_t tt = (size_t)blockIdx.x * 256 + threadIdx.x;
    size_t base = tt * 4;
    if (base >= (size_t)N * 256) return;
    int f0 = (int)(base & 255);
    float sc2 = scale ? scale[base >> 8] : 1.0f;
    ushort4 v = *(const ushort4*)(t + base);
    float r[4] = {b2f(v.x), b2f(v.y), b2f(v.z), b2f(v.w)};
    ushort4 o;
    u16* op = (u16*)&o;
#pragma unroll
    for (int j = 0; j < 4; j++) {
        int f = f0 + j;
        float mean = stat[f] * invN;
        float var = stat[256 + f] * invN - mean * mean;
        float rstd = rsqrtf(var + 1e-5f);
        float sc = rstd * gamma[f];
        float sh = beta[f] - mean * sc;
        op[j] = f2b(fmaxf(r[j] * sc + sh, 0.0f) * sc2);
    }
    *(ushort4*)(h + base) = o;
}

// ---------------- final dot: out[t] = z[t,:] . Wf + bf ----------------

__global__ void k_dot(const u16* __restrict__ z, const float* __restrict__ Wf,
                      const float* __restrict__ bf, float* __restrict__ out, int M) {
    int wave = threadIdx.x >> 6;
    int lane = threadIdx.x & 63;
    int t = blockIdx.x * 4 + wave;
    if (t >= M) return;
    int f0 = lane * 4;
    ushort4 zv = *(const ushort4*)(z + (size_t)t * 256 + f0);
    float4 wv = *(const float4*)(Wf + f0);
    float acc = b2f(zv.x) * wv.x + b2f(zv.y) * wv.y +
                b2f(zv.z) * wv.z + b2f(zv.w) * wv.w;
    for (int off = 32; off > 0; off >>= 1) acc += __shfl_down(acc, off, 64);
    if (lane == 0) out[t] = acc + bf[0];
}

// ---------------- host ----------------

extern "C" void kernel_launch(void* const* d_in, const int* in_sizes, int n_in,
                              void* d_out, int out_size, void* d_ws, size_t ws_size,
                              hipStream_t stream) {
    const int D = 128, H = 256;
    const int N = in_sizes[0] / D;   // 50000
    const int E = in_sizes[1] / 2;   // 800000
    const int M = in_sizes[2];       // 10000

    const float* x = (const float*)d_in[0];
    const int* ei = (const int*)d_in[1];
    const int* tnid = (const int*)d_in[2];
    const float* W1 = (const float*)d_in[3];
    const float* W2 = (const float*)d_in[5];
    const float* W3 = (const float*)d_in[7];
    const float* g1 = (const float*)d_in[9];
    const float* be1 = (const float*)d_in[10];
    const float* g2 = (const float*)d_in[11];
    const float* be2 = (const float*)d_in[12];
    const float* g3 = (const float*)d_in[13];
    const float* be3 = (const float*)d_in[14];
    const float* Wl = (const float*)d_in[15];
    const float* bl = (const float*)d_in[16];
    const float* Wf = (const float*)d_in[17];
    const float* bfp = (const float*)d_in[18];
    float* out = (float*)d_out;

    char* w = (char*)d_ws;
    size_t off = 0;
    auto carve = [&](size_t bytes) -> void* {
        void* p = w + off;
        off = (off + bytes + 255) & ~(size_t)255;
        return p;
    };

    int* deg = (int*)carve((size_t)N * 4);
    float* stat = (float*)carve(3 * 512 * 4);
    size_t zero_span = off;                     // deg + stats zeroed in one memset
    int* flags = (int*)carve(256);
    int* rowptr = (int*)carve((size_t)(N + 1) * 4);
    int* cursor = (int*)carve((size_t)N * 4);
    int* bsums = (int*)carve(256 * 4);
    int* btops = (int*)carve(256 * 4);
    float* disq = (float*)carve((size_t)N * 4);
    int* ssrc = (int*)carve((size_t)E * 4);
    u16* Wt1 = (u16*)carve((size_t)H * D * 2);
    u16* Wt2 = (u16*)carve((size_t)H * H * 2);
    u16* Wt3 = (u16*)carve((size_t)H * H * 2);
    u16* Wtl = (u16*)carve((size_t)H * H * 2);
    u16* xb = (u16*)carve((size_t)N * D * 2);   // x pre-scaled; reused as z later
    u16* aggx = (u16*)carve((size_t)N * D * 2); // gathered x (128 feat)
    u16* aggh = (u16*)carve((size_t)N * H * 2); // gathered h (256 feat)
    u16* tb = (u16*)carve((size_t)N * H * 2);   // GEMM out (pre-BN), bf16
    u16* hb = (u16*)carve((size_t)N * H * 2);   // post-BN h (pre-scaled for L1,2)
    u16* z = xb;

    const int NB = (N + 255) / 256;
    const int EB = (E + 255) / 256;
    const float invN = 1.0f / (float)N;

    hipMemsetAsync(d_ws, 0, zero_span, stream);

    k_detect<<<1, 64, 0, stream>>>(ei, tnid, flags);
    k_count<<<EB, 256, 0, stream>>>(ei, flags, deg, E);
    k_bsum<<<NB, 256, 0, stream>>>(deg, bsums, N);
    k_btop<<<1, 256, 0, stream>>>(bsums, btops, NB);
    k_scan3<<<NB, 256, 0, stream>>>(deg, btops, rowptr, cursor, disq, N, E);
    k_fill<<<EB, 256, 0, stream>>>(ei, flags, cursor, ssrc, E);
    k_cvtx<<<(N * D / 4 + 255) / 256, 256, 0, stream>>>(x, disq, xb, N * D);
    k_wt<<<896, 256, 0, stream>>>(W1, W2, W3, Wl, Wt1, Wt2, Wt3, Wtl);

    const int GB = (N + 63) / 64;               // 782
    const int AB = (N + 3) / 4;                 // 12500
    const int SB = (N + 63) / 64;               // 782
    const int PB = (int)(((size_t)N * H / 4 + 255) / 256);  // 12500

    // layer 1: agg(x') -> GEMM -> BN (aggregate-before-GEMM by linearity)
    k_gather128<<<AB, 256, 0, stream>>>(xb, rowptr, ssrc, disq, aggx, N);
    k_gemm<<<GB, 256, 0, stream>>>(aggx, Wt1, tb, nullptr, flags, N, 128, nullptr, 0);
    k_bnstat<<<SB, 256, 0, stream>>>(tb, stat, N);
    k_bnapply<<<PB, 256, 0, stream>>>(tb, stat, g1, be1, hb, N, invN, disq);
    // layer 2
    k_gather256<<<AB, 256, 0, stream>>>(hb, rowptr, ssrc, disq, aggh, N);
    k_gemm<<<GB, 256, 0, stream>>>(aggh, Wt2, tb, nullptr, flags, N, 256, nullptr, 0);
    k_bnstat<<<SB, 256, 0, stream>>>(tb, stat + 512, N);
    k_bnapply<<<PB, 256, 0, stream>>>(tb, stat + 512, g2, be2, hb, N, invN, disq);
    // layer 3 (output NOT pre-scaled: feeds dense final layer)
    k_gather256<<<AB, 256, 0, stream>>>(hb, rowptr, ssrc, disq, aggh, N);
    k_gemm<<<GB, 256, 0, stream>>>(aggh, Wt3, tb, nullptr, flags, N, 256, nullptr, 0);
    k_bnstat<<<SB, 256, 0, stream>>>(tb, stat + 1024, N);
    k_bnapply<<<PB, 256, 0, stream>>>(tb, stat + 1024, g3, be3, hb, N, invN, nullptr);

    // final: z = relu(hb[tnid] @ Wl + bl) ; out = z @ Wf + bf
    k_gemm<<<(M + 63) / 64, 256, 0, stream>>>(hb, Wtl, z, tnid, flags, M, 256, bl, 1);
    k_dot<<<(M + 3) / 4, 256, 0, stream>>>(z, Wf, bfp, out, M);
}

// Round 6
// 509.156 us; speedup vs baseline: 2.4715x; 1.4718x over previous
//
#include <hip/hip_runtime.h>

typedef unsigned short u16;
typedef __attribute__((ext_vector_type(8))) short short8;
typedef __attribute__((ext_vector_type(4))) float f32x4;

#define DEVFN static __device__ __forceinline__

DEVFN float b2f(u16 u) {
    union { float f; unsigned v; } x; x.v = ((unsigned)u) << 16; return x.f;
}
DEVFN u16 f2b(float f) {
    union { float f; unsigned v; } x; x.f = f;
    unsigned r = x.v + 0x7fffu + ((x.v >> 16) & 1u);
    return (u16)(r >> 16);
}

// ---------------- dtype probe: int64 vs int32 indices ----------------
__global__ void k_detect(const int* __restrict__ ei, const int* __restrict__ tn,
                         int* __restrict__ flags) {
    if (threadIdx.x == 0 && blockIdx.x == 0) {
        int orv = 0;
        for (int i = 1; i < 64; i += 2) orv |= ei[i];
        flags[0] = (orv == 0) ? 1 : 0;
        int orv2 = 0;
        for (int i = 1; i < 64; i += 2) orv2 |= tn[i];
        flags[1] = (orv2 == 0) ? 1 : 0;
    }
}

// ---------------- graph build ----------------

__global__ void k_count(const int* __restrict__ ei, const int* __restrict__ flags,
                        int* __restrict__ cnt, int E) {
    int e = blockIdx.x * 256 + threadIdx.x;
    if (e < E) {
        int m = flags[0];
        atomicAdd(&cnt[ei[(size_t)e << m]], 1);
    }
}

__global__ void k_bsum(const int* __restrict__ cnt, int* __restrict__ bsums, int N) {
    __shared__ int s[256];
    int t = threadIdx.x;
    int i = blockIdx.x * 256 + t;
    int v = (i < N) ? cnt[i] : 0;
    s[t] = v; __syncthreads();
    for (int off = 128; off > 0; off >>= 1) {
        if (t < off) s[t] += s[t + off];
        __syncthreads();
    }
    if (t == 0) bsums[blockIdx.x] = s[0];
}

__global__ void k_btop(const int* __restrict__ bsums, int* __restrict__ btops, int NB) {
    __shared__ int s[256];
    int t = threadIdx.x;
    int v = (t < NB) ? bsums[t] : 0;
    s[t] = v; __syncthreads();
    for (int off = 1; off < 256; off <<= 1) {
        int x = (t >= off) ? s[t - off] : 0;
        __syncthreads();
        s[t] += x;
        __syncthreads();
    }
    btops[t] = s[t] - v;  // exclusive
}

__global__ void k_scan3(const int* __restrict__ cnt, const int* __restrict__ btops,
                        int* __restrict__ rowptr, int* __restrict__ cursor,
                        float* __restrict__ disq, int N, int E) {
    __shared__ int s[256];
    int t = threadIdx.x;
    int i = blockIdx.x * 256 + t;
    int v = (i < N) ? cnt[i] : 0;
    s[t] = v; __syncthreads();
    for (int off = 1; off < 256; off <<= 1) {
        int x = (t >= off) ? s[t - off] : 0;
        __syncthreads();
        s[t] += x;
        __syncthreads();
    }
    int excl = s[t] - v + btops[blockIdx.x];
    if (i < N) {
        rowptr[i] = excl;
        cursor[i] = excl;
        disq[i] = rsqrtf((float)(v + 1));  // +1 self loop
        if (i == N - 1) rowptr[N] = E;
    }
}

__global__ void k_fill(const int* __restrict__ ei, const int* __restrict__ flags,
                       int* __restrict__ cursor, int* __restrict__ ssrc, int E) {
    int e = blockIdx.x * 256 + threadIdx.x;
    if (e < E) {
        int m = flags[0];
        int r = ei[(size_t)e << m];
        int c = ei[(size_t)(E + e) << m];
        int p = atomicAdd(&cursor[r], 1);
        ssrc[p] = c;
    }
}

// ---------------- fp32 -> bf16 convert + pre-scale by disq[row] (x, 128 feat) ----------------
__global__ void k_cvtx(const float* __restrict__ x, const float* __restrict__ disq,
                       u16* __restrict__ xb, int n) {
    int i = (blockIdx.x * 256 + threadIdx.x) * 4;
    if (i >= n) return;
    float d = disq[i >> 7];
    float4 v = *(const float4*)(x + i);
    ushort4 o;
    o.x = f2b(v.x * d); o.y = f2b(v.y * d); o.z = f2b(v.z * d); o.w = f2b(v.w * d);
    *(ushort4*)(xb + i) = o;
}

// ---------------- weight convert+transpose: T[n*K+k] = bf16(W[k*256+n]) ----------------
__global__ void k_wt(const float* __restrict__ W1, const float* __restrict__ W2,
                     const float* __restrict__ W3, const float* __restrict__ Wl,
                     u16* __restrict__ T1, u16* __restrict__ T2,
                     u16* __restrict__ T3, u16* __restrict__ Tl) {
    int t = blockIdx.x * 256 + threadIdx.x;  // 0 .. 229375
    const float* W; u16* T; int K; int idx;
    if (t < 32768)        { W = W1; T = T1; K = 128; idx = t; }
    else if (t < 98304)   { W = W2; T = T2; K = 256; idx = t - 32768; }
    else if (t < 163840)  { W = W3; T = T3; K = 256; idx = t - 98304; }
    else                  { W = Wl; T = Tl; K = 256; idx = t - 163840; }
    int k = idx >> 8, n = idx & 255;
    T[(size_t)n * K + k] = f2b(W[(size_t)k * 256 + n]);
}

// ---------------- register-B MFMA GEMM + fused BN stats ----------------
// C[M][256] = A[M][K] @ W[K][256]. Each wave: B-frags for a 64-col window in
// VGPRs (4 tiles x KS ksteps), streams 16-row groups: 8 A-loads -> 32 MFMAs.
// Block = 4 waves x 4 row-groups over a 256-row strip; grid (ceil(G/16), 4).
// Optional fused per-column sum/sumsq (fp32, pre-bias) -> stat via LDS+atomics.

template<int KS>
__global__ __launch_bounds__(256, 2) void k_gemm_rb(
        const u16* __restrict__ A, const u16* __restrict__ Wt, u16* __restrict__ C,
        const int* __restrict__ idx, const int* __restrict__ flags,
        int Gtot, float* __restrict__ stat, const float* __restrict__ bias, int relu) {
    constexpr int K = KS * 32;
    __shared__ float sbuf[4][2][64];
    int wv = threadIdx.x >> 6;
    int lane = threadIdx.x & 63;
    int quad = lane >> 4;
    int mr = lane & 15;
    int colbase = blockIdx.y * 64;
    int g0 = blockIdx.x * 16;

    // B fragments: col (colbase + j*16 + mr), k-slice (s*32 + quad*8 .. +8)
    short8 Bf[4][KS];
#pragma unroll
    for (int j = 0; j < 4; j++)
#pragma unroll
        for (int s = 0; s < KS; s++)
            Bf[j][s] = *(const short8*)(Wt + (size_t)(colbase + j * 16 + mr) * K + s * 32 + quad * 8);

    float bv[4] = {0.f, 0.f, 0.f, 0.f};
    if (bias) {
#pragma unroll
        for (int j = 0; j < 4; j++) bv[j] = bias[colbase + j * 16 + mr];
    }

    float sreg[4] = {0.f, 0.f, 0.f, 0.f};
    float s2reg[4] = {0.f, 0.f, 0.f, 0.f};
    int f = idx ? flags[1] : 0;

    for (int g = wv; g < 16; g += 4) {
        int gg = g0 + g;
        if (gg >= Gtot) continue;
        int row = gg * 16 + mr;
        int arow = idx ? idx[(size_t)row << f] : row;
        const u16* Ap = A + (size_t)arow * K + quad * 8;

        short8 Af[KS];
#pragma unroll
        for (int s = 0; s < KS; s++) Af[s] = *(const short8*)(Ap + s * 32);

        f32x4 acc[4];
#pragma unroll
        for (int j = 0; j < 4; j++) acc[j] = (f32x4){0.f, 0.f, 0.f, 0.f};
#pragma unroll
        for (int s = 0; s < KS; s++)
#pragma unroll
            for (int j = 0; j < 4; j++)
                acc[j] = __builtin_amdgcn_mfma_f32_16x16x32_bf16(Af[s], Bf[j][s], acc[j], 0, 0, 0);

        // C/D layout: tile row = quad*4 + r, tile col = mr
        size_t cb = (size_t)(gg * 16 + quad * 4) * 256 + colbase + mr;
#pragma unroll
        for (int j = 0; j < 4; j++) {
            float s_ = 0.f, s2_ = 0.f;
#pragma unroll
            for (int r = 0; r < 4; r++) {
                float v = acc[j][r];
                s_ += v; s2_ += v * v;
                v += bv[j];
                if (relu) v = fmaxf(v, 0.f);
                C[cb + (size_t)r * 256 + j * 16] = f2b(v);
            }
            sreg[j] += s_;
            s2reg[j] += s2_;
        }
    }

    if (stat) {
#pragma unroll
        for (int j = 0; j < 4; j++) {
            float s_ = sreg[j], s2_ = s2reg[j];
            s_ += __shfl_xor(s_, 16, 64);  s_ += __shfl_xor(s_, 32, 64);
            s2_ += __shfl_xor(s2_, 16, 64); s2_ += __shfl_xor(s2_, 32, 64);
            if (quad == 0) {
                sbuf[wv][0][j * 16 + mr] = s_;
                sbuf[wv][1][j * 16 + mr] = s2_;
            }
        }
        __syncthreads();
        int t = threadIdx.x;
        if (t < 128) {
            int which = t >> 6, c = t & 63;
            float v = sbuf[0][which][c] + sbuf[1][which][c] +
                      sbuf[2][which][c] + sbuf[3][which][c];
            atomicAdd(&stat[which * 256 + colbase + c], v);
        }
    }
}

// ---------------- CSR gather: dst[i] = disq[i] * (src[i] + sum_c src[c]) ----------------

__global__ __launch_bounds__(256) void k_gather256(
        const u16* __restrict__ src, const int* __restrict__ rowptr,
        const int* __restrict__ ssrc, const float* __restrict__ disq,
        u16* __restrict__ dst, int N) {
    int wave = threadIdx.x >> 6;
    int lane = threadIdx.x & 63;
    int i = blockIdx.x * 4 + wave;
    if (i >= N) return;
    int f0 = lane * 4;
    const u16* base = src + f0;
    ushort4 sv = *(const ushort4*)(base + (size_t)i * 256);
    float a0 = b2f(sv.x), a1 = b2f(sv.y), a2 = b2f(sv.z), a3 = b2f(sv.w);
    int s = rowptr[i], e = rowptr[i + 1];
    int p = s;
    for (; p + 4 <= e; p += 4) {
        int c0 = ssrc[p], c1 = ssrc[p + 1], c2 = ssrc[p + 2], c3 = ssrc[p + 3];
        ushort4 v0 = *(const ushort4*)(base + (size_t)c0 * 256);
        ushort4 v1 = *(const ushort4*)(base + (size_t)c1 * 256);
        ushort4 v2 = *(const ushort4*)(base + (size_t)c2 * 256);
        ushort4 v3 = *(const ushort4*)(base + (size_t)c3 * 256);
        a0 += (b2f(v0.x) + b2f(v1.x)) + (b2f(v2.x) + b2f(v3.x));
        a1 += (b2f(v0.y) + b2f(v1.y)) + (b2f(v2.y) + b2f(v3.y));
        a2 += (b2f(v0.z) + b2f(v1.z)) + (b2f(v2.z) + b2f(v3.z));
        a3 += (b2f(v0.w) + b2f(v1.w)) + (b2f(v2.w) + b2f(v3.w));
    }
    for (; p < e; p++) {
        int c = ssrc[p];
        ushort4 v = *(const ushort4*)(base + (size_t)c * 256);
        a0 += b2f(v.x); a1 += b2f(v.y); a2 += b2f(v.z); a3 += b2f(v.w);
    }
    float di = disq[i];
    ushort4 o;
    o.x = f2b(a0 * di); o.y = f2b(a1 * di); o.z = f2b(a2 * di); o.w = f2b(a3 * di);
    *(ushort4*)(dst + (size_t)i * 256 + f0) = o;
}

__global__ __launch_bounds__(256) void k_gather128(
        const u16* __restrict__ src, const int* __restrict__ rowptr,
        const int* __restrict__ ssrc, const float* __restrict__ disq,
        u16* __restrict__ dst, int N) {
    int wave = threadIdx.x >> 6;
    int lane = threadIdx.x & 63;
    int i = blockIdx.x * 4 + wave;
    if (i >= N) return;
    int f0 = lane * 2;
    const u16* base = src + f0;
    ushort2 sv = *(const ushort2*)(base + (size_t)i * 128);
    float a0 = b2f(sv.x), a1 = b2f(sv.y);
    int s = rowptr[i], e = rowptr[i + 1];
    int p = s;
    for (; p + 4 <= e; p += 4) {
        int c0 = ssrc[p], c1 = ssrc[p + 1], c2 = ssrc[p + 2], c3 = ssrc[p + 3];
        ushort2 v0 = *(const ushort2*)(base + (size_t)c0 * 128);
        ushort2 v1 = *(const ushort2*)(base + (size_t)c1 * 128);
        ushort2 v2 = *(const ushort2*)(base + (size_t)c2 * 128);
        ushort2 v3 = *(const ushort2*)(base + (size_t)c3 * 128);
        a0 += (b2f(v0.x) + b2f(v1.x)) + (b2f(v2.x) + b2f(v3.x));
        a1 += (b2f(v0.y) + b2f(v1.y)) + (b2f(v2.y) + b2f(v3.y));
    }
    for (; p < e; p++) {
        int c = ssrc[p];
        ushort2 v = *(const ushort2*)(base + (size_t)c * 128);
        a0 += b2f(v.x); a1 += b2f(v.y);
    }
    float di = disq[i];
    ushort2 o;
    o.x = f2b(a0 * di); o.y = f2b(a1 * di);
    *(ushort2*)(dst + (size_t)i * 128 + f0) = o;
}

// ---------------- BN apply + relu (+ optional disq pre-scale) -> bf16 h ----------------

__global__ void k_bnapply(const u16* __restrict__ t, const float* __restrict__ stat,
                          const float* __restrict__ gamma, const float* __restrict__ beta,
                          u16* __restrict__ h, int N, float invN,
                          const float* __restrict__ scale) {
    size_t tt = (size_t)blockIdx.x * 256 + threadIdx.x;
    size_t base = tt * 4;
    if (base >= (size_t)N * 256) return;
    int f0 = (int)(base & 255);
    float sc2 = scale ? scale[base >> 8] : 1.0f;
    ushort4 v = *(const ushort4*)(t + base);
    float r[4] = {b2f(v.x), b2f(v.y), b2f(v.z), b2f(v.w)};
    ushort4 o;
    u16* op = (u16*)&o;
#pragma unroll
    for (int j = 0; j < 4; j++) {
        int f = f0 + j;
        float mean = stat[f] * invN;
        float var = stat[256 + f] * invN - mean * mean;
        float rstd = rsqrtf(var + 1e-5f);
        float sc = rstd * gamma[f];
        float sh = beta[f] - mean * sc;
        op[j] = f2b(fmaxf(r[j] * sc + sh, 0.0f) * sc2);
    }
    *(ushort4*)(h + base) = o;
}

// ---------------- final dot: out[t] = z[t,:] . Wf + bf ----------------

__global__ void k_dot(const u16* __restrict__ z, const float* __restrict__ Wf,
                      const float* __restrict__ bf, float* __restrict__ out, int M) {
    int wave = threadIdx.x >> 6;
    int lane = threadIdx.x & 63;
    int t = blockIdx.x * 4 + wave;
    if (t >= M) return;
    int f0 = lane * 4;
    ushort4 zv = *(const ushort4*)(z + (size_t)t * 256 + f0);
    float4 wv = *(const float4*)(Wf + f0);
    float acc = b2f(zv.x) * wv.x + b2f(zv.y) * wv.y +
                b2f(zv.z) * wv.z + b2f(zv.w) * wv.w;
    for (int off = 32; off > 0; off >>= 1) acc += __shfl_down(acc, off, 64);
    if (lane == 0) out[t] = acc + bf[0];
}

// ---------------- host ----------------

extern "C" void kernel_launch(void* const* d_in, const int* in_sizes, int n_in,
                              void* d_out, int out_size, void* d_ws, size_t ws_size,
                              hipStream_t stream) {
    const int D = 128, H = 256;
    const int N = in_sizes[0] / D;   // 50000
    const int E = in_sizes[1] / 2;   // 800000
    const int M = in_sizes[2];       // 10000

    const float* x = (const float*)d_in[0];
    const int* ei = (const int*)d_in[1];
    const int* tnid = (const int*)d_in[2];
    const float* W1 = (const float*)d_in[3];
    const float* W2 = (const float*)d_in[5];
    const float* W3 = (const float*)d_in[7];
    const float* g1 = (const float*)d_in[9];
    const float* be1 = (const float*)d_in[10];
    const float* g2 = (const float*)d_in[11];
    const float* be2 = (const float*)d_in[12];
    const float* g3 = (const float*)d_in[13];
    const float* be3 = (const float*)d_in[14];
    const float* Wl = (const float*)d_in[15];
    const float* bl = (const float*)d_in[16];
    const float* Wf = (const float*)d_in[17];
    const float* bfp = (const float*)d_in[18];
    float* out = (float*)d_out;

    char* w = (char*)d_ws;
    size_t off = 0;
    auto carve = [&](size_t bytes) -> void* {
        void* p = w + off;
        off = (off + bytes + 255) & ~(size_t)255;
        return p;
    };

    int* deg = (int*)carve((size_t)N * 4);
    float* stat = (float*)carve(3 * 512 * 4);
    size_t zero_span = off;                     // deg + stats zeroed in one memset
    int* flags = (int*)carve(256);
    int* rowptr = (int*)carve((size_t)(N + 1) * 4);
    int* cursor = (int*)carve((size_t)N * 4);
    int* bsums = (int*)carve(256 * 4);
    int* btops = (int*)carve(256 * 4);
    float* disq = (float*)carve((size_t)N * 4);
    int* ssrc = (int*)carve((size_t)E * 4);
    u16* Wt1 = (u16*)carve((size_t)H * D * 2);
    u16* Wt2 = (u16*)carve((size_t)H * H * 2);
    u16* Wt3 = (u16*)carve((size_t)H * H * 2);
    u16* Wtl = (u16*)carve((size_t)H * H * 2);
    u16* xb = (u16*)carve((size_t)N * D * 2);   // x pre-scaled; reused as z later
    u16* aggx = (u16*)carve((size_t)N * D * 2); // gathered x (128 feat)
    u16* aggh = (u16*)carve((size_t)N * H * 2); // gathered h (256 feat)
    u16* tb = (u16*)carve((size_t)N * H * 2);   // GEMM out (pre-BN), bf16
    u16* hb = (u16*)carve((size_t)N * H * 2);   // post-BN h (pre-scaled for L1,2)
    u16* z = xb;

    const int NB = (N + 255) / 256;
    const int EB = (E + 255) / 256;
    const float invN = 1.0f / (float)N;

    hipMemsetAsync(d_ws, 0, zero_span, stream);

    k_detect<<<1, 64, 0, stream>>>(ei, tnid, flags);
    k_count<<<EB, 256, 0, stream>>>(ei, flags, deg, E);
    k_bsum<<<NB, 256, 0, stream>>>(deg, bsums, N);
    k_btop<<<1, 256, 0, stream>>>(bsums, btops, NB);
    k_scan3<<<NB, 256, 0, stream>>>(deg, btops, rowptr, cursor, disq, N, E);
    k_fill<<<EB, 256, 0, stream>>>(ei, flags, cursor, ssrc, E);
    k_cvtx<<<(N * D / 4 + 255) / 256, 256, 0, stream>>>(x, disq, xb, N * D);
    k_wt<<<896, 256, 0, stream>>>(W1, W2, W3, Wl, Wt1, Wt2, Wt3, Wtl);

    const int Gn = N / 16;                       // 3125 row-groups (N % 16 == 0)
    const int Gm = M / 16;                       // 625
    dim3 gemm_grid((Gn + 15) / 16, 4);           // (196, 4)
    dim3 gemm_grid_m((Gm + 15) / 16, 4);         // (40, 4)
    const int AB = (N + 3) / 4;                  // 12500
    const int PB = (int)(((size_t)N * H / 4 + 255) / 256);  // 12500

    // layer 1: agg(x') -> GEMM(+stats) -> BN apply
    k_gather128<<<AB, 256, 0, stream>>>(xb, rowptr, ssrc, disq, aggx, N);
    k_gemm_rb<4><<<gemm_grid, 256, 0, stream>>>(aggx, Wt1, tb, nullptr, flags, Gn, stat, nullptr, 0);
    k_bnapply<<<PB, 256, 0, stream>>>(tb, stat, g1, be1, hb, N, invN, disq);
    // layer 2
    k_gather256<<<AB, 256, 0, stream>>>(hb, rowptr, ssrc, disq, aggh, N);
    k_gemm_rb<8><<<gemm_grid, 256, 0, stream>>>(aggh, Wt2, tb, nullptr, flags, Gn, stat + 512, nullptr, 0);
    k_bnapply<<<PB, 256, 0, stream>>>(tb, stat + 512, g2, be2, hb, N, invN, disq);
    // layer 3 (output NOT pre-scaled: feeds dense final layer)
    k_gather256<<<AB, 256, 0, stream>>>(hb, rowptr, ssrc, disq, aggh, N);
    k_gemm_rb<8><<<gemm_grid, 256, 0, stream>>>(aggh, Wt3, tb, nullptr, flags, Gn, stat + 1024, nullptr, 0);
    k_bnapply<<<PB, 256, 0, stream>>>(tb, stat + 1024, g3, be3, hb, N, invN, nullptr);

    // final: z = relu(hb[tnid] @ Wl + bl) ; out = z @ Wf + bf
    k_gemm_rb<8><<<gemm_grid_m, 256, 0, stream>>>(hb, Wtl, z, tnid, flags, Gm, nullptr, bl, 1);
    k_dot<<<(M + 3) / 4, 256, 0, stream>>>(z, Wf, bfp, out, M);
}